// Round 2
// baseline (821.054 us; speedup 1.0000x reference)
//
#include <hip/hip_runtime.h>
#include <stdint.h>
#include <math.h>

#define NTOK 8192
#define DIM  1024
#define FDIM 4096
#define NEXP 8

typedef __bf16 bf16x8 __attribute__((ext_vector_type(8)));
typedef float floatx4 __attribute__((ext_vector_type(4)));
typedef unsigned int u32;

__device__ __forceinline__ unsigned short f2b(float f) {
  union { float f; unsigned u; } v; v.f = f;
  return (unsigned short)((v.u + 0x7fffu + ((v.u >> 16) & 1u)) >> 16);
}

__device__ __forceinline__ float gelu_f(float x) {
  // tanh-form GELU via sigmoid: 0.5x(1+tanh(u)) = x*sigma(2u). One v_exp_f32.
  float u = 1.5957691216f * x * (1.0f + 0.044715f * x * x);
  return x / (1.0f + __expf(-u));
}

// async 16B/lane global->LDS. LDS dest is wave-uniform base; lane i lands at base + i*16.
__device__ __forceinline__ void async_cp16(const unsigned short* g, unsigned short* l) {
  __builtin_amdgcn_global_load_lds((__attribute__((address_space(1))) u32*)g,
                                   (__attribute__((address_space(3))) u32*)l, 16, 0, 0);
}

// Recompute the per-expert prefix scan from raw counts ctrl[0..7].
// Replaces the old scan_k<<<1,1>>> launch (counts are visible across the
// kernel-launch boundary). Returns tile->expert mapping for tile mt.
__device__ __forceinline__ void expert_tile(const int* __restrict__ ctrl, int mt,
                                            int& e, int& m0, int& cnt, int& ntiles) {
  int off = 0, ts = 0;
  e = 0; m0 = 0; cnt = 0;
#pragma unroll
  for (int i = 0; i < NEXP; i++) {
    int c = ctrl[i];
    int nt = (c + 127) >> 7;
    if (mt >= ts && mt < ts + nt) {
      e = i;
      m0 = off + (mt - ts) * 128;
      cnt = c - (mt - ts) * 128;
    }
    ts += nt; off += c;
  }
  ntiles = ts;
  if (cnt > 128) cnt = 128;
}

// ---------------- router ----------------
__global__ __launch_bounds__(256) void router_k(
    const float* __restrict__ x, const float* __restrict__ Wr,
    const float* __restrict__ br, int* __restrict__ idx,
    float* __restrict__ gate, int* __restrict__ ctrl) {
  int t = (int)((blockIdx.x * 256 + threadIdx.x) >> 6);
  int lane = threadIdx.x & 63;
  const float* xr = x + (size_t)t * DIM;
  float acc[NEXP];
#pragma unroll
  for (int e = 0; e < NEXP; e++) acc[e] = 0.f;
#pragma unroll
  for (int k = 0; k < DIM / 64; k++) {
    int d = k * 64 + lane;
    float xv = xr[d];
    const float4* wp = (const float4*)(Wr + (size_t)d * NEXP);
    float4 w0 = wp[0], w1 = wp[1];
    acc[0] += xv * w0.x; acc[1] += xv * w0.y;
    acc[2] += xv * w0.z; acc[3] += xv * w0.w;
    acc[4] += xv * w1.x; acc[5] += xv * w1.y;
    acc[6] += xv * w1.z; acc[7] += xv * w1.w;
  }
#pragma unroll
  for (int off = 32; off > 0; off >>= 1) {
#pragma unroll
    for (int e = 0; e < NEXP; e++) acc[e] += __shfl_xor(acc[e], off, 64);
  }
  if (lane == 0) {
    float mx = -3.4e38f; int best = 0;
#pragma unroll
    for (int e = 0; e < NEXP; e++) {
      float l = acc[e] + br[e];
      if (l > mx) { mx = l; best = e; }
    }
    float s = 0.f;
#pragma unroll
    for (int e = 0; e < NEXP; e++) s += expf(acc[e] + br[e] - mx);
    idx[t] = best;
    gate[t] = 1.f / s;
    atomicAdd(&ctrl[best], 1);
  }
}

// ---------------- scatter tokens, fp32 -> bf16 ----------------
// ctrl: [0..7] counts (from router), [17..24] fill counters
__global__ __launch_bounds__(256) void scatter_k(
    const float* __restrict__ x, const int* __restrict__ idx,
    const float* __restrict__ gate, int* __restrict__ ctrl,
    unsigned short* __restrict__ Xb, int* __restrict__ token_dst,
    float* __restrict__ gate_p) {
  __shared__ int s_pos;
  int t = blockIdx.x;
  if (threadIdx.x == 0) {
    int e = idx[t];
    int off = 0;
#pragma unroll
    for (int i = 0; i < NEXP; i++) off += (i < e) ? ctrl[i] : 0;
    s_pos = off + atomicAdd(&ctrl[17 + e], 1);
  }
  __syncthreads();
  int pos = s_pos;
  if (threadIdx.x == 0) { token_dst[pos] = t; gate_p[pos] = gate[t]; }
  float4 v = ((const float4*)(x + (size_t)t * DIM))[threadIdx.x];
  ushort4 o;
  o.x = f2b(v.x); o.y = f2b(v.y); o.z = f2b(v.z); o.w = f2b(v.w);
  ((ushort4*)(Xb + (size_t)pos * DIM))[threadIdx.x] = o;
}

// ---------------- fused transpose + cvt for BOTH weight tensors ----------------
// z < NEXP:  W1 expert z, [DIM][FDIM] -> W1b [FDIM][DIM]
// z >= NEXP: W2 expert z-8, [FDIM][DIM] -> W2b [DIM][FDIM]
__global__ __launch_bounds__(256) void transpose_cvt2_k(
    const float* __restrict__ W1, unsigned short* __restrict__ W1b,
    const float* __restrict__ W2, unsigned short* __restrict__ W2b) {
  __shared__ float tile[64][65];
  __shared__ unsigned short obuf[64][72];
  int z = blockIdx.z;
  const float* in; unsigned short* out; int R, C, tc, tr;
  if (z < NEXP) {
    in = W1 + (size_t)z * DIM * FDIM; out = W1b + (size_t)z * DIM * FDIM;
    R = DIM; C = FDIM; tc = blockIdx.x; tr = blockIdx.y;
  } else {
    int e = z - NEXP;
    in = W2 + (size_t)e * FDIM * DIM; out = W2b + (size_t)e * FDIM * DIM;
    R = FDIM; C = DIM; tc = blockIdx.y; tr = blockIdx.x;
  }
  int c0 = tc * 64, r0 = tr * 64;
  int t = threadIdx.x;
  int rr = t >> 4, cc = (t & 15) * 4;
#pragma unroll
  for (int k = 0; k < 64; k += 16) {
    float4 v = *(const float4*)&in[(size_t)(r0 + rr + k) * C + c0 + cc];
    tile[rr + k][cc] = v.x; tile[rr + k][cc + 1] = v.y;
    tile[rr + k][cc + 2] = v.z; tile[rr + k][cc + 3] = v.w;
  }
  __syncthreads();
  int cr = t >> 4, rb = (t & 15) * 4;
#pragma unroll
  for (int k = 0; k < 64; k += 16) {
    ushort4 o;
    o.x = f2b(tile[rb + 0][cr + k]); o.y = f2b(tile[rb + 1][cr + k]);
    o.z = f2b(tile[rb + 2][cr + k]); o.w = f2b(tile[rb + 3][cr + k]);
    *(ushort4*)&obuf[cr + k][rb] = o;
  }
  __syncthreads();
  int r2 = t >> 3, c8 = (t & 7) * 8;
#pragma unroll
  for (int k = 0; k < 64; k += 32)
    *(uint4*)&out[(size_t)(c0 + r2 + k) * R + r0 + c8] = *(const uint4*)&obuf[r2 + k][c8];
}

// ---------------- GEMM1: H = gelu(Xb @ W1b^T + b1) ----------------
__global__ __launch_bounds__(256) void gemm1_k(
    const unsigned short* __restrict__ Amat, const unsigned short* __restrict__ Bmat,
    const float* __restrict__ bias, unsigned short* __restrict__ Hout,
    const int* __restrict__ ctrl) {
  // 16384 shorts for A/B staging; epilogue reuses as 4 waves x 64 rows x stride-68
  __shared__ unsigned short lds[17408];
  unsigned short* A_lds = lds;
  unsigned short* B_lds = lds + 8192;

  int mt = blockIdx.y;
  int e, m0, cnt, ntiles;
  expert_tile(ctrl, mt, e, m0, cnt, ntiles);
  if (mt >= ntiles) return;
  int c0 = blockIdx.x * 128;
  const unsigned short* B = Bmat + (size_t)e * FDIM * DIM;

  int tid = threadIdx.x;
  int lane = tid & 63, wave = tid >> 6;
  int wr = wave >> 1, wc = wave & 1;
  int grp = lane >> 4, m16 = lane & 15;

  int lr = lane >> 3;
  int cchunk = (lane & 7) ^ lr;
  const unsigned short* srcA[4];
  const unsigned short* srcB[4];
  unsigned short* dstA[4];
  unsigned short* dstB[4];
#pragma unroll
  for (int q = 0; q < 4; q++) {
    int brow = wave * 32 + q * 8;
    int arow = m0 + brow + lr; if (arow > NTOK - 1) arow = NTOK - 1;
    srcA[q] = Amat + (size_t)arow * DIM + cchunk * 8;
    srcB[q] = B + (size_t)(c0 + brow + lr) * DIM + cchunk * 8;
    dstA[q] = A_lds + brow * 64;
    dstB[q] = B_lds + brow * 64;
  }

  floatx4 acc[4][4];
  floatx4 zero = {0.f, 0.f, 0.f, 0.f};
#pragma unroll
  for (int i = 0; i < 4; i++)
#pragma unroll
    for (int j = 0; j < 4; j++) acc[i][j] = zero;

  int x7 = m16 & 7;
  int rowA[4], rowB[4];
#pragma unroll
  for (int i = 0; i < 4; i++) {
    rowA[i] = (wr * 64 + i * 16 + m16) * 64;
    rowB[i] = (wc * 64 + i * 16 + m16) * 64;
  }

  for (int kk = 0; kk < DIM; kk += 64) {
#pragma unroll
    for (int q = 0; q < 4; q++) async_cp16(srcA[q], dstA[q]);
#pragma unroll
    for (int q = 0; q < 4; q++) async_cp16(srcB[q], dstB[q]);
#pragma unroll
    for (int q = 0; q < 4; q++) { srcA[q] += 64; srcB[q] += 64; }
    __syncthreads();
    bf16x8 af[2][4], bfr[2][4];
#pragma unroll
    for (int h = 0; h < 2; h++) {
      int off = (((h << 2) | grp) ^ x7) << 3;
#pragma unroll
      for (int i = 0; i < 4; i++) {
        af[h][i]  = *(const bf16x8*)&A_lds[rowA[i] + off];
        bfr[h][i] = *(const bf16x8*)&B_lds[rowB[i] + off];
      }
    }
#pragma unroll
    for (int h = 0; h < 2; h++)
#pragma unroll
      for (int i = 0; i < 4; i++)
#pragma unroll
        for (int j = 0; j < 4; j++)
          acc[i][j] = __builtin_amdgcn_mfma_f32_16x16x32_bf16(af[h][i], bfr[h][j], acc[i][j], 0, 0, 0);
    __syncthreads();
  }

  float bs[4];
#pragma unroll
  for (int j = 0; j < 4; j++) bs[j] = bias[(size_t)e * FDIM + c0 + wc * 64 + j * 16 + m16];

  // Epilogue staging at stride 68 shorts/row: bank = (34*row + col/2) mod 32.
  // Write instr (fixed i,j,r): rows grp*4+r spread over 4 bank-octets x 8 col-banks
  // -> all 32 banks, 2-way only (free, m136).
  unsigned short* st = lds + wave * 4352;
#pragma unroll
  for (int i = 0; i < 4; i++)
#pragma unroll
    for (int j = 0; j < 4; j++)
#pragma unroll
      for (int r = 0; r < 4; r++)
        st[(i * 16 + grp * 4 + r) * 68 + j * 16 + m16] = f2b(gelu_f(acc[i][j][r] + bs[j]));
  __syncthreads();
  int lr8 = lane >> 3, c8 = (lane & 7) * 8;
  int colb = c0 + wc * 64 + c8;
#pragma unroll
  for (int rr = 0; rr < 8; rr++) {
    int row = rr * 8 + lr8;
    int gm = wr * 64 + row;
    if (gm < cnt) {
      // rows are 136 B (8B-aligned): read two uint2, store one uint4
      uint2 a = *(const uint2*)&st[row * 68 + c8];
      uint2 b = *(const uint2*)&st[row * 68 + c8 + 4];
      uint4 v; v.x = a.x; v.y = a.y; v.z = b.x; v.w = b.y;
      *(uint4*)&Hout[(size_t)(m0 + gm) * FDIM + colb] = v;
    }
  }
}

// ---------------- GEMM2 split-K=2, fused epilogue via fp32 atomics ----------------
// out[t] += (acc_chunk + (chunk==0 ? b2 : 0)) * gate   (out pre-zeroed by memset)
// Exactly 2 addends per element -> bit-deterministic regardless of arrival order.
__global__ __launch_bounds__(256) void gemm2_k(
    const unsigned short* __restrict__ Hmat, const unsigned short* __restrict__ W2b,
    const float* __restrict__ b2, float* __restrict__ out,
    const int* __restrict__ token_dst, const float* __restrict__ gate_p,
    const int* __restrict__ ctrl) {
  __shared__ unsigned short lds[16384];
  unsigned short* A_lds = lds;
  unsigned short* B_lds = lds + 8192;

  int mt = blockIdx.y;
  int e, m0, cnt, ntiles;
  expert_tile(ctrl, mt, e, m0, cnt, ntiles);
  if (mt >= ntiles) return;
  int c0 = blockIdx.x * 128;
  int k0 = blockIdx.z * (FDIM / 2);
  const unsigned short* B = W2b + (size_t)e * DIM * FDIM + k0;
  const unsigned short* A = Hmat + k0;

  int tid = threadIdx.x;
  int lane = tid & 63, wave = tid >> 6;
  int wr = wave >> 1, wc = wave & 1;
  int grp = lane >> 4, m16 = lane & 15;

  int lr = lane >> 3;
  int cchunk = (lane & 7) ^ lr;
  const unsigned short* srcA[4];
  const unsigned short* srcB[4];
  unsigned short* dstA[4];
  unsigned short* dstB[4];
#pragma unroll
  for (int q = 0; q < 4; q++) {
    int brow = wave * 32 + q * 8;
    int arow = m0 + brow + lr; if (arow > NTOK - 1) arow = NTOK - 1;
    srcA[q] = A + (size_t)arow * FDIM + cchunk * 8;
    srcB[q] = B + (size_t)(c0 + brow + lr) * FDIM + cchunk * 8;
    dstA[q] = A_lds + brow * 64;
    dstB[q] = B_lds + brow * 64;
  }

  floatx4 acc[4][4];
  floatx4 zero = {0.f, 0.f, 0.f, 0.f};
#pragma unroll
  for (int i = 0; i < 4; i++)
#pragma unroll
    for (int j = 0; j < 4; j++) acc[i][j] = zero;

  int x7 = m16 & 7;
  int rowA[4], rowB[4];
#pragma unroll
  for (int i = 0; i < 4; i++) {
    rowA[i] = (wr * 64 + i * 16 + m16) * 64;
    rowB[i] = (wc * 64 + i * 16 + m16) * 64;
  }

  for (int kk = 0; kk < FDIM / 2; kk += 64) {
#pragma unroll
    for (int q = 0; q < 4; q++) async_cp16(srcA[q], dstA[q]);
#pragma unroll
    for (int q = 0; q < 4; q++) async_cp16(srcB[q], dstB[q]);
#pragma unroll
    for (int q = 0; q < 4; q++) { srcA[q] += 64; srcB[q] += 64; }
    __syncthreads();
    bf16x8 af[2][4], bfr[2][4];
#pragma unroll
    for (int h = 0; h < 2; h++) {
      int off = (((h << 2) | grp) ^ x7) << 3;
#pragma unroll
      for (int i = 0; i < 4; i++) {
        af[h][i]  = *(const bf16x8*)&A_lds[rowA[i] + off];
        bfr[h][i] = *(const bf16x8*)&B_lds[rowB[i] + off];
      }
    }
#pragma unroll
    for (int h = 0; h < 2; h++)
#pragma unroll
      for (int i = 0; i < 4; i++)
#pragma unroll
        for (int j = 0; j < 4; j++)
          acc[i][j] = __builtin_amdgcn_mfma_f32_16x16x32_bf16(af[h][i], bfr[h][j], acc[i][j], 0, 0, 0);
    __syncthreads();
  }

  float bs[4];
#pragma unroll
  for (int j = 0; j < 4; j++)
    bs[j] = (blockIdx.z == 0) ? b2[(size_t)e * DIM + c0 + wc * 64 + j * 16 + m16] : 0.f;

#pragma unroll
  for (int i = 0; i < 4; i++) {
    int rb = wr * 64 + i * 16 + grp * 4;
#pragma unroll
    for (int r = 0; r < 4; r++) {
      int lm = rb + r;
      if (lm < cnt) {
        int t = token_dst[m0 + lm];
        float g = gate_p[m0 + lm];
#pragma unroll
        for (int j = 0; j < 4; j++) {
          int col = c0 + wc * 64 + j * 16 + m16;
          atomicAdd(&out[(size_t)t * DIM + col], (acc[i][j][r] + bs[j]) * g);
        }
      }
    }
  }
}

extern "C" void kernel_launch(void* const* d_in, const int* in_sizes, int n_in,
                              void* d_out, int out_size, void* d_ws, size_t ws_size,
                              hipStream_t stream) {
  const float* x  = (const float*)d_in[0];
  const float* W1 = (const float*)d_in[1];
  const float* b1 = (const float*)d_in[2];
  const float* W2 = (const float*)d_in[3];
  const float* b2 = (const float*)d_in[4];
  const float* Wr = (const float*)d_in[5];
  const float* br = (const float*)d_in[6];
  float* out = (float*)d_out;

  char* w = (char*)d_ws;
  int*   ctrl      = (int*)w;
  int*   idx       = (int*)(w + 1024);
  float* gate      = (float*)(w + 1024 + 4 * NTOK);
  int*   token_dst = (int*)(w + 1024 + 8 * NTOK);
  float* gate_p    = (float*)(w + 1024 + 12 * NTOK);
  unsigned short* Xb  = (unsigned short*)(w + (1ull << 18));    // 16.8 MB
  unsigned short* H   = (unsigned short*)(w + (20ull << 20));   // 67.1 MB
  unsigned short* W1b = (unsigned short*)(w + (88ull << 20));   // 67.1 MB
  unsigned short* W2b = (unsigned short*)(w + (156ull << 20));  // 67.1 MB

  hipMemsetAsync(ctrl, 0, 256, stream);
  hipMemsetAsync(out, 0, (size_t)NTOK * DIM * 4, stream);
  router_k<<<NTOK / 4, 256, 0, stream>>>(x, Wr, br, idx, gate, ctrl);
  scatter_k<<<NTOK, 256, 0, stream>>>(x, idx, gate, ctrl, Xb, token_dst, gate_p);
  transpose_cvt2_k<<<dim3(64, 16, 16), 256, 0, stream>>>(W1, W1b, W2, W2b);
  gemm1_k<<<dim3(FDIM / 128, 72), 256, 0, stream>>>(Xb, W1b, b1, H, ctrl);
  gemm2_k<<<dim3(DIM / 128, 72, 2), 256, 0, stream>>>(H, W2b, b2, out, token_dst, gate_p, ctrl);
}

// Round 3
// 781.159 us; speedup vs baseline: 1.0511x; 1.0511x over previous
//
#include <hip/hip_runtime.h>
#include <stdint.h>
#include <math.h>

#define NTOK 8192
#define DIM  1024
#define FDIM 4096
#define NEXP 8

typedef __bf16 bf16x8 __attribute__((ext_vector_type(8)));
typedef float floatx4 __attribute__((ext_vector_type(4)));
typedef unsigned int u32;

__device__ __forceinline__ unsigned short f2b(float f) {
  union { float f; unsigned u; } v; v.f = f;
  return (unsigned short)((v.u + 0x7fffu + ((v.u >> 16) & 1u)) >> 16);
}

__device__ __forceinline__ float gelu_f(float x) {
  // tanh-form GELU via sigmoid: 0.5x(1+tanh(u)) = x*sigma(2u). One v_exp_f32.
  float u = 1.5957691216f * x * (1.0f + 0.044715f * x * x);
  return x / (1.0f + __expf(-u));
}

// async 16B/lane global->LDS. LDS dest is wave-uniform base; lane i lands at base + i*16.
__device__ __forceinline__ void async_cp16(const unsigned short* g, unsigned short* l) {
  __builtin_amdgcn_global_load_lds((__attribute__((address_space(1))) u32*)g,
                                   (__attribute__((address_space(3))) u32*)l, 16, 0, 0);
}

// Recompute the per-expert prefix scan from raw counts ctrl[0..7].
// (Replaces a scan_k<<<1,1>>> launch; counts are visible across the launch boundary.)
__device__ __forceinline__ void expert_tile(const int* __restrict__ ctrl, int mt,
                                            int& e, int& m0, int& cnt, int& ntiles) {
  int off = 0, ts = 0;
  e = 0; m0 = 0; cnt = 0;
#pragma unroll
  for (int i = 0; i < NEXP; i++) {
    int c = ctrl[i];
    int nt = (c + 127) >> 7;
    if (mt >= ts && mt < ts + nt) {
      e = i;
      m0 = off + (mt - ts) * 128;
      cnt = c - (mt - ts) * 128;
    }
    ts += nt; off += c;
  }
  ntiles = ts;
  if (cnt > 128) cnt = 128;
}

// ---------------- router ----------------
__global__ __launch_bounds__(256) void router_k(
    const float* __restrict__ x, const float* __restrict__ Wr,
    const float* __restrict__ br, int* __restrict__ idx,
    float* __restrict__ gate, int* __restrict__ ctrl) {
  int t = (int)((blockIdx.x * 256 + threadIdx.x) >> 6);
  int lane = threadIdx.x & 63;
  const float* xr = x + (size_t)t * DIM;
  float acc[NEXP];
#pragma unroll
  for (int e = 0; e < NEXP; e++) acc[e] = 0.f;
#pragma unroll
  for (int k = 0; k < DIM / 64; k++) {
    int d = k * 64 + lane;
    float xv = xr[d];
    const float4* wp = (const float4*)(Wr + (size_t)d * NEXP);
    float4 w0 = wp[0], w1 = wp[1];
    acc[0] += xv * w0.x; acc[1] += xv * w0.y;
    acc[2] += xv * w0.z; acc[3] += xv * w0.w;
    acc[4] += xv * w1.x; acc[5] += xv * w1.y;
    acc[6] += xv * w1.z; acc[7] += xv * w1.w;
  }
#pragma unroll
  for (int off = 32; off > 0; off >>= 1) {
#pragma unroll
    for (int e = 0; e < NEXP; e++) acc[e] += __shfl_xor(acc[e], off, 64);
  }
  if (lane == 0) {
    float mx = -3.4e38f; int best = 0;
#pragma unroll
    for (int e = 0; e < NEXP; e++) {
      float l = acc[e] + br[e];
      if (l > mx) { mx = l; best = e; }
    }
    float s = 0.f;
#pragma unroll
    for (int e = 0; e < NEXP; e++) s += expf(acc[e] + br[e] - mx);
    idx[t] = best;
    gate[t] = 1.f / s;
    atomicAdd(&ctrl[best], 1);
  }
}

// ---------------- scatter tokens, fp32 -> bf16 ----------------
// ctrl: [0..7] counts (from router), [17..24] fill counters
__global__ __launch_bounds__(256) void scatter_k(
    const float* __restrict__ x, const int* __restrict__ idx,
    const float* __restrict__ gate, int* __restrict__ ctrl,
    unsigned short* __restrict__ Xb, int* __restrict__ token_dst,
    float* __restrict__ gate_p) {
  __shared__ int s_pos;
  int t = blockIdx.x;
  if (threadIdx.x == 0) {
    int e = idx[t];
    int off = 0;
#pragma unroll
    for (int i = 0; i < NEXP; i++) off += (i < e) ? ctrl[i] : 0;
    s_pos = off + atomicAdd(&ctrl[17 + e], 1);
  }
  __syncthreads();
  int pos = s_pos;
  if (threadIdx.x == 0) { token_dst[pos] = t; gate_p[pos] = gate[t]; }
  float4 v = ((const float4*)(x + (size_t)t * DIM))[threadIdx.x];
  ushort4 o;
  o.x = f2b(v.x); o.y = f2b(v.y); o.z = f2b(v.z); o.w = f2b(v.w);
  ((ushort4*)(Xb + (size_t)pos * DIM))[threadIdx.x] = o;
}

// ---------------- fused transpose + cvt for BOTH weight tensors ----------------
// z < NEXP:  W1 expert z, [DIM][FDIM] -> W1b [FDIM][DIM]
// z >= NEXP: W2 expert z-8, [FDIM][DIM] -> W2b [DIM][FDIM]
__global__ __launch_bounds__(256) void transpose_cvt2_k(
    const float* __restrict__ W1, unsigned short* __restrict__ W1b,
    const float* __restrict__ W2, unsigned short* __restrict__ W2b) {
  __shared__ float tile[64][65];
  __shared__ unsigned short obuf[64][72];
  int z = blockIdx.z;
  const float* in; unsigned short* out; int R, C, tc, tr;
  if (z < NEXP) {
    in = W1 + (size_t)z * DIM * FDIM; out = W1b + (size_t)z * DIM * FDIM;
    R = DIM; C = FDIM; tc = blockIdx.x; tr = blockIdx.y;
  } else {
    int e = z - NEXP;
    in = W2 + (size_t)e * FDIM * DIM; out = W2b + (size_t)e * FDIM * DIM;
    R = FDIM; C = DIM; tc = blockIdx.y; tr = blockIdx.x;
  }
  int c0 = tc * 64, r0 = tr * 64;
  int t = threadIdx.x;
  int rr = t >> 4, cc = (t & 15) * 4;
#pragma unroll
  for (int k = 0; k < 64; k += 16) {
    float4 v = *(const float4*)&in[(size_t)(r0 + rr + k) * C + c0 + cc];
    tile[rr + k][cc] = v.x; tile[rr + k][cc + 1] = v.y;
    tile[rr + k][cc + 2] = v.z; tile[rr + k][cc + 3] = v.w;
  }
  __syncthreads();
  int cr = t >> 4, rb = (t & 15) * 4;
#pragma unroll
  for (int k = 0; k < 64; k += 16) {
    ushort4 o;
    o.x = f2b(tile[rb + 0][cr + k]); o.y = f2b(tile[rb + 1][cr + k]);
    o.z = f2b(tile[rb + 2][cr + k]); o.w = f2b(tile[rb + 3][cr + k]);
    *(ushort4*)&obuf[cr + k][rb] = o;
  }
  __syncthreads();
  int r2 = t >> 3, c8 = (t & 7) * 8;
#pragma unroll
  for (int k = 0; k < 64; k += 32)
    *(uint4*)&out[(size_t)(c0 + r2 + k) * R + r0 + c8] = *(const uint4*)&obuf[r2 + k][c8];
}

// ---------------- GEMM1: H = gelu(Xb @ W1b^T + b1) ----------------
__global__ __launch_bounds__(256) void gemm1_k(
    const unsigned short* __restrict__ Amat, const unsigned short* __restrict__ Bmat,
    const float* __restrict__ bias, unsigned short* __restrict__ Hout,
    const int* __restrict__ ctrl) {
  // 16384 shorts for A/B staging; epilogue reuses as 4 waves x 64 rows x stride-68
  __shared__ unsigned short lds[17408];
  unsigned short* A_lds = lds;
  unsigned short* B_lds = lds + 8192;

  int mt = blockIdx.y;
  int e, m0, cnt, ntiles;
  expert_tile(ctrl, mt, e, m0, cnt, ntiles);
  if (mt >= ntiles) return;
  int c0 = blockIdx.x * 128;
  const unsigned short* B = Bmat + (size_t)e * FDIM * DIM;

  int tid = threadIdx.x;
  int lane = tid & 63, wave = tid >> 6;
  int wr = wave >> 1, wc = wave & 1;
  int grp = lane >> 4, m16 = lane & 15;

  int lr = lane >> 3;
  int cchunk = (lane & 7) ^ lr;
  const unsigned short* srcA[4];
  const unsigned short* srcB[4];
  unsigned short* dstA[4];
  unsigned short* dstB[4];
#pragma unroll
  for (int q = 0; q < 4; q++) {
    int brow = wave * 32 + q * 8;
    int arow = m0 + brow + lr; if (arow > NTOK - 1) arow = NTOK - 1;
    srcA[q] = Amat + (size_t)arow * DIM + cchunk * 8;
    srcB[q] = B + (size_t)(c0 + brow + lr) * DIM + cchunk * 8;
    dstA[q] = A_lds + brow * 64;
    dstB[q] = B_lds + brow * 64;
  }

  floatx4 acc[4][4];
  floatx4 zero = {0.f, 0.f, 0.f, 0.f};
#pragma unroll
  for (int i = 0; i < 4; i++)
#pragma unroll
    for (int j = 0; j < 4; j++) acc[i][j] = zero;

  int x7 = m16 & 7;
  int rowA[4], rowB[4];
#pragma unroll
  for (int i = 0; i < 4; i++) {
    rowA[i] = (wr * 64 + i * 16 + m16) * 64;
    rowB[i] = (wc * 64 + i * 16 + m16) * 64;
  }

  for (int kk = 0; kk < DIM; kk += 64) {
#pragma unroll
    for (int q = 0; q < 4; q++) async_cp16(srcA[q], dstA[q]);
#pragma unroll
    for (int q = 0; q < 4; q++) async_cp16(srcB[q], dstB[q]);
#pragma unroll
    for (int q = 0; q < 4; q++) { srcA[q] += 64; srcB[q] += 64; }
    __syncthreads();
    bf16x8 af[2][4], bfr[2][4];
#pragma unroll
    for (int h = 0; h < 2; h++) {
      int off = (((h << 2) | grp) ^ x7) << 3;
#pragma unroll
      for (int i = 0; i < 4; i++) {
        af[h][i]  = *(const bf16x8*)&A_lds[rowA[i] + off];
        bfr[h][i] = *(const bf16x8*)&B_lds[rowB[i] + off];
      }
    }
#pragma unroll
    for (int h = 0; h < 2; h++)
#pragma unroll
      for (int i = 0; i < 4; i++)
#pragma unroll
        for (int j = 0; j < 4; j++)
          acc[i][j] = __builtin_amdgcn_mfma_f32_16x16x32_bf16(af[h][i], bfr[h][j], acc[i][j], 0, 0, 0);
    __syncthreads();
  }

  float bs[4];
#pragma unroll
  for (int j = 0; j < 4; j++) bs[j] = bias[(size_t)e * FDIM + c0 + wc * 64 + j * 16 + m16];

  // Epilogue staging at stride 68 shorts/row: bank = (34*row + col/2) mod 32.
  // Write instr (fixed i,j,r): rows grp*4+r spread over 4 bank-octets x 8 col-banks
  // -> all 32 banks, 2-way only (free, m136).
  unsigned short* st = lds + wave * 4352;
#pragma unroll
  for (int i = 0; i < 4; i++)
#pragma unroll
    for (int j = 0; j < 4; j++)
#pragma unroll
      for (int r = 0; r < 4; r++)
        st[(i * 16 + grp * 4 + r) * 68 + j * 16 + m16] = f2b(gelu_f(acc[i][j][r] + bs[j]));
  __syncthreads();
  int lr8 = lane >> 3, c8 = (lane & 7) * 8;
  int colb = c0 + wc * 64 + c8;
#pragma unroll
  for (int rr = 0; rr < 8; rr++) {
    int row = rr * 8 + lr8;
    int gm = wr * 64 + row;
    if (gm < cnt) {
      // rows are 136 B (8B-aligned): read two uint2, store one uint4
      uint2 a = *(const uint2*)&st[row * 68 + c8];
      uint2 b = *(const uint2*)&st[row * 68 + c8 + 4];
      uint4 v; v.x = a.x; v.y = a.y; v.z = b.x; v.w = b.y;
      *(uint4*)&Hout[(size_t)(m0 + gm) * FDIM + colb] = v;
    }
  }
}

// ---------------- GEMM2 full-K, double-buffered LDS (2-phase pipeline) ----------------
// out[t] = (H @ W2b^T + b2) * gate, plain stores (every compact row = one token).
// Grid is 576 blocks (2.25/CU): no inter-block overlap exists, so the next
// K-tile's global_load_lds is issued AFTER the barrier and flies during the
// MFMA phase. One barrier per K-step; its vmcnt(0) drain finds the loads
// already landed. 64 KB LDS -> 2 blocks/CU static, grid is the binding limit.
__global__ __launch_bounds__(256) void gemm2_k(
    const unsigned short* __restrict__ Hmat, const unsigned short* __restrict__ W2b,
    const float* __restrict__ b2, float* __restrict__ out,
    const int* __restrict__ token_dst, const float* __restrict__ gate_p,
    const int* __restrict__ ctrl) {
  __shared__ unsigned short lds[32768];  // 2 x (A 8192 + B 8192)

  int mt = blockIdx.y;
  int e, m0, cnt, ntiles;
  expert_tile(ctrl, mt, e, m0, cnt, ntiles);
  if (mt >= ntiles) return;
  int c0 = blockIdx.x * 128;
  const unsigned short* B = W2b + (size_t)e * DIM * FDIM;

  int tid = threadIdx.x;
  int lane = tid & 63, wave = tid >> 6;
  int wr = wave >> 1, wc = wave & 1;
  int grp = lane >> 4, m16 = lane & 15;

  int lr = lane >> 3;
  int cchunk = (lane & 7) ^ lr;
  const unsigned short* srcA[4];
  const unsigned short* srcB[4];
  int dstoff[4];
#pragma unroll
  for (int q = 0; q < 4; q++) {
    int brow = wave * 32 + q * 8;
    int arow = m0 + brow + lr; if (arow > NTOK - 1) arow = NTOK - 1;
    srcA[q] = Hmat + (size_t)arow * FDIM + cchunk * 8;
    srcB[q] = B + (size_t)(c0 + brow + lr) * FDIM + cchunk * 8;
    dstoff[q] = brow * 64;
  }

  floatx4 acc[4][4];
  floatx4 zero = {0.f, 0.f, 0.f, 0.f};
#pragma unroll
  for (int i = 0; i < 4; i++)
#pragma unroll
    for (int j = 0; j < 4; j++) acc[i][j] = zero;

  int x7 = m16 & 7;
  int rowA[4], rowB[4];
#pragma unroll
  for (int i = 0; i < 4; i++) {
    rowA[i] = (wr * 64 + i * 16 + m16) * 64;
    rowB[i] = (wc * 64 + i * 16 + m16) * 64;
  }

  // prologue: stage K-tile 0 into buffer 0
#pragma unroll
  for (int q = 0; q < 4; q++) async_cp16(srcA[q], lds + dstoff[q]);
#pragma unroll
  for (int q = 0; q < 4; q++) async_cp16(srcB[q], lds + 8192 + dstoff[q]);
#pragma unroll
  for (int q = 0; q < 4; q++) { srcA[q] += 64; srcB[q] += 64; }

  const int kIters = FDIM / 64;  // 64
  int p = 0;
  for (int it = 0; it < kIters; ++it) {
    __syncthreads();  // drains vmcnt: current buffer's loads (issued last iter) landed
    unsigned short* Acur = lds + p * 16384;
    unsigned short* Bcur = Acur + 8192;
    if (it + 1 < kIters) {
      unsigned short* An = lds + (p ^ 1) * 16384;
      unsigned short* Bn = An + 8192;
#pragma unroll
      for (int q = 0; q < 4; q++) async_cp16(srcA[q], An + dstoff[q]);
#pragma unroll
      for (int q = 0; q < 4; q++) async_cp16(srcB[q], Bn + dstoff[q]);
#pragma unroll
      for (int q = 0; q < 4; q++) { srcA[q] += 64; srcB[q] += 64; }
    }
    bf16x8 af[2][4], bfr[2][4];
#pragma unroll
    for (int h = 0; h < 2; h++) {
      int off = (((h << 2) | grp) ^ x7) << 3;
#pragma unroll
      for (int i = 0; i < 4; i++) {
        af[h][i]  = *(const bf16x8*)&Acur[rowA[i] + off];
        bfr[h][i] = *(const bf16x8*)&Bcur[rowB[i] + off];
      }
    }
#pragma unroll
    for (int h = 0; h < 2; h++)
#pragma unroll
      for (int i = 0; i < 4; i++)
#pragma unroll
        for (int j = 0; j < 4; j++)
          acc[i][j] = __builtin_amdgcn_mfma_f32_16x16x32_bf16(af[h][i], bfr[h][j], acc[i][j], 0, 0, 0);
    p ^= 1;
  }

  float bs[4];
#pragma unroll
  for (int j = 0; j < 4; j++) bs[j] = b2[(size_t)e * DIM + c0 + wc * 64 + j * 16 + m16];

#pragma unroll
  for (int i = 0; i < 4; i++) {
    int rb = wr * 64 + i * 16 + grp * 4;
#pragma unroll
    for (int r = 0; r < 4; r++) {
      int lm = rb + r;
      if (lm < cnt) {
        int t = token_dst[m0 + lm];
        float g = gate_p[m0 + lm];
#pragma unroll
        for (int j = 0; j < 4; j++) {
          int col = c0 + wc * 64 + j * 16 + m16;
          out[(size_t)t * DIM + col] = (acc[i][j][r] + bs[j]) * g;
        }
      }
    }
  }
}

extern "C" void kernel_launch(void* const* d_in, const int* in_sizes, int n_in,
                              void* d_out, int out_size, void* d_ws, size_t ws_size,
                              hipStream_t stream) {
  const float* x  = (const float*)d_in[0];
  const float* W1 = (const float*)d_in[1];
  const float* b1 = (const float*)d_in[2];
  const float* W2 = (const float*)d_in[3];
  const float* b2 = (const float*)d_in[4];
  const float* Wr = (const float*)d_in[5];
  const float* br = (const float*)d_in[6];
  float* out = (float*)d_out;

  char* w = (char*)d_ws;
  int*   ctrl      = (int*)w;
  int*   idx       = (int*)(w + 1024);
  float* gate      = (float*)(w + 1024 + 4 * NTOK);
  int*   token_dst = (int*)(w + 1024 + 8 * NTOK);
  float* gate_p    = (float*)(w + 1024 + 12 * NTOK);
  unsigned short* Xb  = (unsigned short*)(w + (1ull << 18));    // 16.8 MB
  unsigned short* H   = (unsigned short*)(w + (20ull << 20));   // 67.1 MB
  unsigned short* W1b = (unsigned short*)(w + (88ull << 20));   // 67.1 MB
  unsigned short* W2b = (unsigned short*)(w + (156ull << 20));  // 67.1 MB

  hipMemsetAsync(ctrl, 0, 256, stream);
  router_k<<<NTOK / 4, 256, 0, stream>>>(x, Wr, br, idx, gate, ctrl);
  scatter_k<<<NTOK, 256, 0, stream>>>(x, idx, gate, ctrl, Xb, token_dst, gate_p);
  transpose_cvt2_k<<<dim3(64, 16, 16), 256, 0, stream>>>(W1, W1b, W2, W2b);
  gemm1_k<<<dim3(FDIM / 128, 72), 256, 0, stream>>>(Xb, W1b, b1, H, ctrl);
  gemm2_k<<<dim3(DIM / 128, 72), 256, 0, stream>>>(H, W2b, b2, out, token_dst, gate_p, ctrl);
}

// Round 4
// 714.773 us; speedup vs baseline: 1.1487x; 1.0929x over previous
//
#include <hip/hip_runtime.h>
#include <stdint.h>
#include <math.h>

#define NTOK 8192
#define DIM  1024
#define FDIM 4096
#define NEXP 8

typedef __bf16 bf16x8 __attribute__((ext_vector_type(8)));
typedef float floatx4 __attribute__((ext_vector_type(4)));
typedef unsigned int u32;

__device__ __forceinline__ unsigned short f2b(float f) {
  union { float f; unsigned u; } v; v.f = f;
  return (unsigned short)((v.u + 0x7fffu + ((v.u >> 16) & 1u)) >> 16);
}

__device__ __forceinline__ float gelu_f(float x) {
  // tanh-form GELU via sigmoid: 0.5x(1+tanh(u)) = x*sigma(2u). One v_exp_f32.
  float u = 1.5957691216f * x * (1.0f + 0.044715f * x * x);
  return x / (1.0f + __expf(-u));
}

// async 16B/lane global->LDS. LDS dest is wave-uniform base; lane i lands at base + i*16.
__device__ __forceinline__ void async_cp16(const unsigned short* g, unsigned short* l) {
  __builtin_amdgcn_global_load_lds((__attribute__((address_space(1))) u32*)g,
                                   (__attribute__((address_space(3))) u32*)l, 16, 0, 0);
}

// Recompute the per-expert prefix scan from raw counts ctrl[0..7].
// (Counts are visible across the kernel-launch boundary; no scan kernel needed.)
__device__ __forceinline__ void expert_tile(const int* __restrict__ ctrl, int mt,
                                            int& e, int& m0, int& cnt, int& ntiles) {
  int off = 0, ts = 0;
  e = 0; m0 = 0; cnt = 0;
#pragma unroll
  for (int i = 0; i < NEXP; i++) {
    int c = ctrl[i];
    int nt = (c + 127) >> 7;
    if (mt >= ts && mt < ts + nt) {
      e = i;
      m0 = off + (mt - ts) * 128;
      cnt = c - (mt - ts) * 128;
    }
    ts += nt; off += c;
  }
  ntiles = ts;
  if (cnt > 128) cnt = 128;
}

// ---------------- router + x fp32->bf16 convert (fused; x read ONCE) ----------------
// Xc is written in TOKEN order (no scatter dependency); gemm1 indirects via perm[].
__global__ __launch_bounds__(256) void router_cvt_k(
    const float* __restrict__ x, const float* __restrict__ Wr,
    const float* __restrict__ br, int* __restrict__ idx,
    float* __restrict__ gate, int* __restrict__ ctrl,
    unsigned short* __restrict__ Xc) {
  int t = (int)((blockIdx.x * 256 + threadIdx.x) >> 6);
  int lane = threadIdx.x & 63;
  const float* xr = x + (size_t)t * DIM;
  unsigned short* xo = Xc + (size_t)t * DIM;
  float acc[NEXP];
#pragma unroll
  for (int e = 0; e < NEXP; e++) acc[e] = 0.f;
#pragma unroll
  for (int k = 0; k < DIM / 64; k++) {
    int d = k * 64 + lane;
    float xv = xr[d];
    xo[d] = f2b(xv);  // coalesced 2B stores: 64 lanes = 128B segment
    const float4* wp = (const float4*)(Wr + (size_t)d * NEXP);
    float4 w0 = wp[0], w1 = wp[1];
    acc[0] += xv * w0.x; acc[1] += xv * w0.y;
    acc[2] += xv * w0.z; acc[3] += xv * w0.w;
    acc[4] += xv * w1.x; acc[5] += xv * w1.y;
    acc[6] += xv * w1.z; acc[7] += xv * w1.w;
  }
#pragma unroll
  for (int off = 32; off > 0; off >>= 1) {
#pragma unroll
    for (int e = 0; e < NEXP; e++) acc[e] += __shfl_xor(acc[e], off, 64);
  }
  if (lane == 0) {
    float mx = -3.4e38f; int best = 0;
#pragma unroll
    for (int e = 0; e < NEXP; e++) {
      float l = acc[e] + br[e];
      if (l > mx) { mx = l; best = e; }
    }
    float s = 0.f;
#pragma unroll
    for (int e = 0; e < NEXP; e++) s += expf(acc[e] + br[e] - mx);
    idx[t] = best;
    gate[t] = 1.f / s;
    atomicAdd(&ctrl[best], 1);
  }
}

// ---------------- build compact permutation (no bulk data movement) ----------------
// perm[pos] = token, gate_p[pos] = gate. ctrl[17..24] are fill counters (memset 0).
__global__ __launch_bounds__(256) void perm_k(
    const int* __restrict__ idx, const float* __restrict__ gate,
    int* __restrict__ ctrl, int* __restrict__ perm, float* __restrict__ gate_p) {
  int t = blockIdx.x * 256 + threadIdx.x;
  int e = idx[t];
  int off = 0;
#pragma unroll
  for (int i = 0; i < NEXP; i++) off += (i < e) ? ctrl[i] : 0;
  int pos = off + atomicAdd(&ctrl[17 + e], 1);
  perm[pos] = t;
  gate_p[pos] = gate[t];
}

// ---------------- fused transpose + cvt for BOTH weight tensors ----------------
// z < NEXP:  W1 expert z, [DIM][FDIM] -> W1b [FDIM][DIM]
// z >= NEXP: W2 expert z-8, [FDIM][DIM] -> W2b [DIM][FDIM]
__global__ __launch_bounds__(256) void transpose_cvt2_k(
    const float* __restrict__ W1, unsigned short* __restrict__ W1b,
    const float* __restrict__ W2, unsigned short* __restrict__ W2b) {
  __shared__ float tile[64][65];
  __shared__ unsigned short obuf[64][72];
  int z = blockIdx.z;
  const float* in; unsigned short* out; int R, C, tc, tr;
  if (z < NEXP) {
    in = W1 + (size_t)z * DIM * FDIM; out = W1b + (size_t)z * DIM * FDIM;
    R = DIM; C = FDIM; tc = blockIdx.x; tr = blockIdx.y;
  } else {
    int e = z - NEXP;
    in = W2 + (size_t)e * FDIM * DIM; out = W2b + (size_t)e * FDIM * DIM;
    R = FDIM; C = DIM; tc = blockIdx.y; tr = blockIdx.x;
  }
  int c0 = tc * 64, r0 = tr * 64;
  int t = threadIdx.x;
  int rr = t >> 4, cc = (t & 15) * 4;
#pragma unroll
  for (int k = 0; k < 64; k += 16) {
    float4 v = *(const float4*)&in[(size_t)(r0 + rr + k) * C + c0 + cc];
    tile[rr + k][cc] = v.x; tile[rr + k][cc + 1] = v.y;
    tile[rr + k][cc + 2] = v.z; tile[rr + k][cc + 3] = v.w;
  }
  __syncthreads();
  int cr = t >> 4, rb = (t & 15) * 4;
#pragma unroll
  for (int k = 0; k < 64; k += 16) {
    ushort4 o;
    o.x = f2b(tile[rb + 0][cr + k]); o.y = f2b(tile[rb + 1][cr + k]);
    o.z = f2b(tile[rb + 2][cr + k]); o.w = f2b(tile[rb + 3][cr + k]);
    *(ushort4*)&obuf[cr + k][rb] = o;
  }
  __syncthreads();
  int r2 = t >> 3, c8 = (t & 7) * 8;
#pragma unroll
  for (int k = 0; k < 64; k += 32)
    *(uint4*)&out[(size_t)(c0 + r2 + k) * R + r0 + c8] = *(const uint4*)&obuf[r2 + k][c8];
}

// ---------------- GEMM1: H = gelu(Xc[perm] @ W1b^T + b1) ----------------
__global__ __launch_bounds__(256) void gemm1_k(
    const unsigned short* __restrict__ Xc, const unsigned short* __restrict__ Bmat,
    const float* __restrict__ bias, unsigned short* __restrict__ Hout,
    const int* __restrict__ ctrl, const int* __restrict__ perm) {
  __shared__ unsigned short lds[16384];  // staging; epilogue reuses (XOR-swizzled)
  unsigned short* A_lds = lds;
  unsigned short* B_lds = lds + 8192;

  int mt = blockIdx.y;
  int e, m0, cnt, ntiles;
  expert_tile(ctrl, mt, e, m0, cnt, ntiles);
  if (mt >= ntiles) return;
  int c0 = blockIdx.x * 128;
  const unsigned short* B = Bmat + (size_t)e * FDIM * DIM;

  int tid = threadIdx.x;
  int lane = tid & 63, wave = tid >> 6;
  int wr = wave >> 1, wc = wave & 1;
  int grp = lane >> 4, m16 = lane & 15;

  int lr = lane >> 3;
  int cchunk = (lane & 7) ^ lr;
  const unsigned short* srcA[4];
  const unsigned short* srcB[4];
  unsigned short* dstA[4];
  unsigned short* dstB[4];
#pragma unroll
  for (int q = 0; q < 4; q++) {
    int brow = wave * 32 + q * 8;
    int p = m0 + brow + lr; if (p > NTOK - 1) p = NTOK - 1;
    int arow = perm[p];  // indirection: A stays in token order, no scatter pass
    srcA[q] = Xc + (size_t)arow * DIM + cchunk * 8;
    srcB[q] = B + (size_t)(c0 + brow + lr) * DIM + cchunk * 8;
    dstA[q] = A_lds + brow * 64;
    dstB[q] = B_lds + brow * 64;
  }

  floatx4 acc[4][4];
  floatx4 zero = {0.f, 0.f, 0.f, 0.f};
#pragma unroll
  for (int i = 0; i < 4; i++)
#pragma unroll
    for (int j = 0; j < 4; j++) acc[i][j] = zero;

  int x7 = m16 & 7;
  int rowA[4], rowB[4];
#pragma unroll
  for (int i = 0; i < 4; i++) {
    rowA[i] = (wr * 64 + i * 16 + m16) * 64;
    rowB[i] = (wc * 64 + i * 16 + m16) * 64;
  }

  for (int kk = 0; kk < DIM; kk += 64) {
#pragma unroll
    for (int q = 0; q < 4; q++) async_cp16(srcA[q], dstA[q]);
#pragma unroll
    for (int q = 0; q < 4; q++) async_cp16(srcB[q], dstB[q]);
#pragma unroll
    for (int q = 0; q < 4; q++) { srcA[q] += 64; srcB[q] += 64; }
    __syncthreads();
    bf16x8 af[2][4], bfr[2][4];
#pragma unroll
    for (int h = 0; h < 2; h++) {
      int off = (((h << 2) | grp) ^ x7) << 3;
#pragma unroll
      for (int i = 0; i < 4; i++) {
        af[h][i]  = *(const bf16x8*)&A_lds[rowA[i] + off];
        bfr[h][i] = *(const bf16x8*)&B_lds[rowB[i] + off];
      }
    }
#pragma unroll
    for (int h = 0; h < 2; h++)
#pragma unroll
      for (int i = 0; i < 4; i++)
#pragma unroll
        for (int j = 0; j < 4; j++)
          acc[i][j] = __builtin_amdgcn_mfma_f32_16x16x32_bf16(af[h][i], bfr[h][j], acc[i][j], 0, 0, 0);
    __syncthreads();
  }

  float bs[4];
#pragma unroll
  for (int j = 0; j < 4; j++) bs[j] = bias[(size_t)e * FDIM + c0 + wc * 64 + j * 16 + m16];

  // Epilogue staging: stride 64, col XOR-swizzled by (((row>>1)&7)<<3).
  // Write (fixed i,j,r): v=(row>>1)&7 distinct per grp -> banks 8*grp + m16/2 = all 32, free.
  // Read: bank-quad = (lane&7) ^ v(lr8) spans all 8 quads, free. LDS stays 32 KB -> 5 blocks/CU.
  unsigned short* st = lds + wave * 4096;
#pragma unroll
  for (int i = 0; i < 4; i++)
#pragma unroll
    for (int j = 0; j < 4; j++)
#pragma unroll
      for (int r = 0; r < 4; r++) {
        int row = i * 16 + grp * 4 + r;
        int scol = (j * 16 + m16) ^ (((row >> 1) & 7) << 3);
        st[row * 64 + scol] = f2b(gelu_f(acc[i][j][r] + bs[j]));
      }
  __syncthreads();
  int lr8 = lane >> 3, c8 = (lane & 7) * 8;
  int colb = c0 + wc * 64 + c8;
#pragma unroll
  for (int rr = 0; rr < 8; rr++) {
    int row = rr * 8 + lr8;
    int gm = wr * 64 + row;
    if (gm < cnt) {
      int scol = c8 ^ (((row >> 1) & 7) << 3);  // 8-aligned: 16B read ok
      *(uint4*)&Hout[(size_t)(m0 + gm) * FDIM + colb] = *(const uint4*)&st[row * 64 + scol];
    }
  }
}

// ---------------- GEMM2 full-K, double-buffered LDS (2-phase pipeline) ----------------
// out[t] = (H @ W2b^T + b2) * gate. Grid 576 blocks (2.25/CU): no inter-block
// overlap exists, so next K-tile's global_load_lds is issued after the barrier
// and flies during the MFMA phase (r3: -40 us vs single-buffer).
__global__ __launch_bounds__(256) void gemm2_k(
    const unsigned short* __restrict__ Hmat, const unsigned short* __restrict__ W2b,
    const float* __restrict__ b2, float* __restrict__ out,
    const int* __restrict__ perm, const float* __restrict__ gate_p,
    const int* __restrict__ ctrl) {
  __shared__ unsigned short lds[32768];  // 2 x (A 8192 + B 8192)

  int mt = blockIdx.y;
  int e, m0, cnt, ntiles;
  expert_tile(ctrl, mt, e, m0, cnt, ntiles);
  if (mt >= ntiles) return;
  int c0 = blockIdx.x * 128;
  const unsigned short* B = W2b + (size_t)e * DIM * FDIM;

  int tid = threadIdx.x;
  int lane = tid & 63, wave = tid >> 6;
  int wr = wave >> 1, wc = wave & 1;
  int grp = lane >> 4, m16 = lane & 15;

  int lr = lane >> 3;
  int cchunk = (lane & 7) ^ lr;
  const unsigned short* srcA[4];
  const unsigned short* srcB[4];
  int dstoff[4];
#pragma unroll
  for (int q = 0; q < 4; q++) {
    int brow = wave * 32 + q * 8;
    int arow = m0 + brow + lr; if (arow > NTOK - 1) arow = NTOK - 1;
    srcA[q] = Hmat + (size_t)arow * FDIM + cchunk * 8;
    srcB[q] = B + (size_t)(c0 + brow + lr) * FDIM + cchunk * 8;
    dstoff[q] = brow * 64;
  }

  floatx4 acc[4][4];
  floatx4 zero = {0.f, 0.f, 0.f, 0.f};
#pragma unroll
  for (int i = 0; i < 4; i++)
#pragma unroll
    for (int j = 0; j < 4; j++) acc[i][j] = zero;

  int x7 = m16 & 7;
  int rowA[4], rowB[4];
#pragma unroll
  for (int i = 0; i < 4; i++) {
    rowA[i] = (wr * 64 + i * 16 + m16) * 64;
    rowB[i] = (wc * 64 + i * 16 + m16) * 64;
  }

  // prologue: stage K-tile 0 into buffer 0
#pragma unroll
  for (int q = 0; q < 4; q++) async_cp16(srcA[q], lds + dstoff[q]);
#pragma unroll
  for (int q = 0; q < 4; q++) async_cp16(srcB[q], lds + 8192 + dstoff[q]);
#pragma unroll
  for (int q = 0; q < 4; q++) { srcA[q] += 64; srcB[q] += 64; }

  const int kIters = FDIM / 64;  // 64
  int p = 0;
  for (int it = 0; it < kIters; ++it) {
    __syncthreads();  // drains vmcnt: current buffer's loads landed
    unsigned short* Acur = lds + p * 16384;
    unsigned short* Bcur = Acur + 8192;
    if (it + 1 < kIters) {
      unsigned short* An = lds + (p ^ 1) * 16384;
      unsigned short* Bn = An + 8192;
#pragma unroll
      for (int q = 0; q < 4; q++) async_cp16(srcA[q], An + dstoff[q]);
#pragma unroll
      for (int q = 0; q < 4; q++) async_cp16(srcB[q], Bn + dstoff[q]);
#pragma unroll
      for (int q = 0; q < 4; q++) { srcA[q] += 64; srcB[q] += 64; }
    }
    bf16x8 af[2][4], bfr[2][4];
#pragma unroll
    for (int h = 0; h < 2; h++) {
      int off = (((h << 2) | grp) ^ x7) << 3;
#pragma unroll
      for (int i = 0; i < 4; i++) {
        af[h][i]  = *(const bf16x8*)&Acur[rowA[i] + off];
        bfr[h][i] = *(const bf16x8*)&Bcur[rowB[i] + off];
      }
    }
#pragma unroll
    for (int h = 0; h < 2; h++)
#pragma unroll
      for (int i = 0; i < 4; i++)
#pragma unroll
        for (int j = 0; j < 4; j++)
          acc[i][j] = __builtin_amdgcn_mfma_f32_16x16x32_bf16(af[h][i], bfr[h][j], acc[i][j], 0, 0, 0);
    p ^= 1;
  }

  float bs[4];
#pragma unroll
  for (int j = 0; j < 4; j++) bs[j] = b2[(size_t)e * DIM + c0 + wc * 64 + j * 16 + m16];

#pragma unroll
  for (int i = 0; i < 4; i++) {
    int rb = wr * 64 + i * 16 + grp * 4;
#pragma unroll
    for (int r = 0; r < 4; r++) {
      int lm = rb + r;
      if (lm < cnt) {
        int t = perm[m0 + lm];
        float g = gate_p[m0 + lm];
#pragma unroll
        for (int j = 0; j < 4; j++) {
          int col = c0 + wc * 64 + j * 16 + m16;
          out[(size_t)t * DIM + col] = (acc[i][j][r] + bs[j]) * g;
        }
      }
    }
  }
}

extern "C" void kernel_launch(void* const* d_in, const int* in_sizes, int n_in,
                              void* d_out, int out_size, void* d_ws, size_t ws_size,
                              hipStream_t stream) {
  const float* x  = (const float*)d_in[0];
  const float* W1 = (const float*)d_in[1];
  const float* b1 = (const float*)d_in[2];
  const float* W2 = (const float*)d_in[3];
  const float* b2 = (const float*)d_in[4];
  const float* Wr = (const float*)d_in[5];
  const float* br = (const float*)d_in[6];
  float* out = (float*)d_out;

  char* w = (char*)d_ws;
  int*   ctrl   = (int*)w;
  int*   idx    = (int*)(w + 1024);
  float* gate   = (float*)(w + 1024 + 4 * NTOK);
  int*   perm   = (int*)(w + 1024 + 8 * NTOK);
  float* gate_p = (float*)(w + 1024 + 12 * NTOK);
  unsigned short* Xc  = (unsigned short*)(w + (1ull << 18));    // 16.8 MB, token order
  unsigned short* H   = (unsigned short*)(w + (20ull << 20));   // 67.1 MB
  unsigned short* W1b = (unsigned short*)(w + (88ull << 20));   // 67.1 MB
  unsigned short* W2b = (unsigned short*)(w + (156ull << 20));  // 67.1 MB

  hipMemsetAsync(ctrl, 0, 256, stream);
  // transpose first: its 402 MB sweep runs before Xc is produced, so Xc stays L3-warm for gemm1
  transpose_cvt2_k<<<dim3(64, 16, 16), 256, 0, stream>>>(W1, W1b, W2, W2b);
  router_cvt_k<<<NTOK / 4, 256, 0, stream>>>(x, Wr, br, idx, gate, ctrl, Xc);
  perm_k<<<NTOK / 256, 256, 0, stream>>>(idx, gate, ctrl, perm, gate_p);
  gemm1_k<<<dim3(FDIM / 128, 72), 256, 0, stream>>>(Xc, W1b, b1, H, ctrl, perm);
  gemm2_k<<<dim3(DIM / 128, 72), 256, 0, stream>>>(H, W2b, b2, out, perm, gate_p, ctrl);
}

// Round 6
// 679.814 us; speedup vs baseline: 1.2078x; 1.0514x over previous
//
#include <hip/hip_runtime.h>
#include <stdint.h>
#include <math.h>

#define NTOK 8192
#define DIM  1024
#define FDIM 4096
#define NEXP 8

typedef __bf16 bf16x8 __attribute__((ext_vector_type(8)));
typedef float floatx4 __attribute__((ext_vector_type(4)));
typedef unsigned int u32;

__device__ __forceinline__ unsigned short f2b(float f) {
  union { float f; unsigned u; } v; v.f = f;
  return (unsigned short)((v.u + 0x7fffu + ((v.u >> 16) & 1u)) >> 16);
}

__device__ __forceinline__ float gelu_f(float x) {
  // tanh-form GELU via sigmoid: 0.5x(1+tanh(u)) = x*sigma(2u). One v_exp_f32.
  float u = 1.5957691216f * x * (1.0f + 0.044715f * x * x);
  return x / (1.0f + __expf(-u));
}

// async 16B/lane global->LDS. LDS dest is wave-uniform base; lane i lands at base + i*16.
__device__ __forceinline__ void async_cp16(const unsigned short* g, unsigned short* l) {
  __builtin_amdgcn_global_load_lds((__attribute__((address_space(1))) u32*)g,
                                   (__attribute__((address_space(3))) u32*)l, 16, 0, 0);
}

// Recompute the per-expert prefix scan from raw counts ctrl[0..7].
__device__ __forceinline__ void expert_tile(const int* __restrict__ ctrl, int mt,
                                            int& e, int& m0, int& cnt, int& ntiles) {
  int off = 0, ts = 0;
  e = 0; m0 = 0; cnt = 0;
#pragma unroll
  for (int i = 0; i < NEXP; i++) {
    int c = ctrl[i];
    int nt = (c + 127) >> 7;
    if (mt >= ts && mt < ts + nt) {
      e = i;
      m0 = off + (mt - ts) * 128;
      cnt = c - (mt - ts) * 128;
    }
    ts += nt; off += c;
  }
  ntiles = ts;
  if (cnt > 128) cnt = 128;
}

// ---------------- router + x fp32->bf16 convert (fused; x read ONCE) ----------------
__global__ __launch_bounds__(256) void router_cvt_k(
    const float* __restrict__ x, const float* __restrict__ Wr,
    const float* __restrict__ br, int* __restrict__ idx,
    float* __restrict__ gate, int* __restrict__ ctrl,
    unsigned short* __restrict__ Xc) {
  int t = (int)((blockIdx.x * 256 + threadIdx.x) >> 6);
  int lane = threadIdx.x & 63;
  const float* xr = x + (size_t)t * DIM;
  unsigned short* xo = Xc + (size_t)t * DIM;
  float acc[NEXP];
#pragma unroll
  for (int e = 0; e < NEXP; e++) acc[e] = 0.f;
#pragma unroll
  for (int k = 0; k < DIM / 64; k++) {
    int d = k * 64 + lane;
    float xv = xr[d];
    xo[d] = f2b(xv);  // coalesced 2B stores
    const float4* wp = (const float4*)(Wr + (size_t)d * NEXP);
    float4 w0 = wp[0], w1 = wp[1];
    acc[0] += xv * w0.x; acc[1] += xv * w0.y;
    acc[2] += xv * w0.z; acc[3] += xv * w0.w;
    acc[4] += xv * w1.x; acc[5] += xv * w1.y;
    acc[6] += xv * w1.z; acc[7] += xv * w1.w;
  }
#pragma unroll
  for (int off = 32; off > 0; off >>= 1) {
#pragma unroll
    for (int e = 0; e < NEXP; e++) acc[e] += __shfl_xor(acc[e], off, 64);
  }
  if (lane == 0) {
    float mx = -3.4e38f; int best = 0;
#pragma unroll
    for (int e = 0; e < NEXP; e++) {
      float l = acc[e] + br[e];
      if (l > mx) { mx = l; best = e; }
    }
    float s = 0.f;
#pragma unroll
    for (int e = 0; e < NEXP; e++) s += expf(acc[e] + br[e] - mx);
    idx[t] = best;
    gate[t] = 1.f / s;
    atomicAdd(&ctrl[best], 1);
  }
}

// ---------------- compact permutation, wave-aggregated atomics ----------------
// 8 ballots + <=8 atomics per wave instead of 64 same-address atomics.
__global__ __launch_bounds__(256) void perm_k(
    const int* __restrict__ idx, const float* __restrict__ gate,
    int* __restrict__ ctrl, int* __restrict__ perm, float* __restrict__ gate_p) {
  int t = blockIdx.x * 256 + threadIdx.x;
  int lane = threadIdx.x & 63;
  int e = idx[t];
  int off = 0;
#pragma unroll
  for (int i = 0; i < NEXP; i++) off += (i < e) ? ctrl[i] : 0;
  int pos = 0;
#pragma unroll
  for (int ei = 0; ei < NEXP; ei++) {
    unsigned long long m = __ballot(e == ei);
    if (m) {
      int leader = (int)__ffsll((long long)m) - 1;
      int base = 0;
      if (lane == leader) base = atomicAdd(&ctrl[17 + ei], (int)__popcll(m));
      base = __shfl(base, leader, 64);
      if (e == ei)
        pos = off + base + (int)__popcll(m & ((1ull << lane) - 1ull));
    }
  }
  perm[pos] = t;
  gate_p[pos] = gate[t];
}

// ---------------- transpose + cvt, single bf16 LDS pass ----------------
// z < NEXP:  W1 expert z, [DIM][FDIM] -> W1b [FDIM][DIM]
// z >= NEXP: W2 expert z-8, [FDIM][DIM] -> W2b [DIM][FDIM]
// Phase 1: read float4 from row pairs, f2b in regs, pack vertical pairs into
// b32 LDS writes at transposed position (stride 68: 4-way on write, ok).
// Phase 2: two b64 reads (8B-aligned at stride 68, ~2-way) -> 16B global store.
__global__ __launch_bounds__(256) void transpose_cvt2_k(
    const float* __restrict__ W1, unsigned short* __restrict__ W1b,
    const float* __restrict__ W2, unsigned short* __restrict__ W2b) {
  __shared__ unsigned short obuf[64][68];
  int z = blockIdx.z;
  const float* in; unsigned short* out; int R, C, tc, tr;
  if (z < NEXP) {
    in = W1 + (size_t)z * DIM * FDIM; out = W1b + (size_t)z * DIM * FDIM;
    R = DIM; C = FDIM; tc = blockIdx.x; tr = blockIdx.y;
  } else {
    int e = z - NEXP;
    in = W2 + (size_t)e * FDIM * DIM; out = W2b + (size_t)e * FDIM * DIM;
    R = FDIM; C = DIM; tc = blockIdx.y; tr = blockIdx.x;
  }
  int c0 = tc * 64, r0 = tr * 64;
  int t = threadIdx.x;
  int rr2 = t >> 4;           // row-pair index 0..15
  int cc = (t & 15) * 4;      // col base
#pragma unroll
  for (int k = 0; k < 2; k++) {
    int rb = rr2 * 2 + 32 * k;
    float4 v0 = *(const float4*)&in[(size_t)(r0 + rb) * C + c0 + cc];
    float4 v1 = *(const float4*)&in[(size_t)(r0 + rb + 1) * C + c0 + cc];
    u32 w0 = (u32)f2b(v0.x) | ((u32)f2b(v1.x) << 16);
    u32 w1 = (u32)f2b(v0.y) | ((u32)f2b(v1.y) << 16);
    u32 w2 = (u32)f2b(v0.z) | ((u32)f2b(v1.z) << 16);
    u32 w3 = (u32)f2b(v0.w) | ((u32)f2b(v1.w) << 16);
    *(u32*)&obuf[cc + 0][rb] = w0;
    *(u32*)&obuf[cc + 1][rb] = w1;
    *(u32*)&obuf[cc + 2][rb] = w2;
    *(u32*)&obuf[cc + 3][rb] = w3;
  }
  __syncthreads();
  int c8 = (t & 7) * 8, r2 = t >> 3;  // 32 rows per k
#pragma unroll
  for (int k = 0; k < 2; k++) {
    int Rr = r2 + 32 * k;
    uint2 a = *(const uint2*)&obuf[Rr][c8];
    uint2 b = *(const uint2*)&obuf[Rr][c8 + 4];
    uint4 v; v.x = a.x; v.y = a.y; v.z = b.x; v.w = b.y;
    *(uint4*)&out[(size_t)(c0 + Rr) * R + r0 + c8] = v;
  }
}

// ---------------- GEMM1: H = gelu(Xc[perm] @ W1b^T + b1), BK=32 double-buffered ----------------
// r3-proven pipeline (issue -> compute -> drain at next barrier) at BK=32 so the
// double buffer fits in 32 KB and occupancy stays 5 blocks/CU.
__global__ __launch_bounds__(256) void gemm1_k(
    const unsigned short* __restrict__ Xc, const unsigned short* __restrict__ Bmat,
    const float* __restrict__ bias, unsigned short* __restrict__ Hout,
    const int* __restrict__ ctrl, const int* __restrict__ perm) {
  __shared__ unsigned short lds[16384];  // 2 buffers x (A 4096 + B 4096 shorts)

  int mt = blockIdx.y;
  int e, m0, cnt, ntiles;
  expert_tile(ctrl, mt, e, m0, cnt, ntiles);
  if (mt >= ntiles) return;
  int c0 = blockIdx.x * 128;
  const unsigned short* B = Bmat + (size_t)e * FDIM * DIM;

  int tid = threadIdx.x;
  int lane = tid & 63, wave = tid >> 6;
  int wr = wave >> 1, wc = wave & 1;
  int grp = lane >> 4, m16 = lane & 15;

  // staging: per cp16 inst a wave covers 16 rows x 32k. Pre-swizzle the global
  // k-chunk so LDS[row][c] holds global chunk c^(row&3) (both-sides rule).
  int lr4 = lane >> 2;
  int kc = (lane & 3) ^ (lr4 & 3);
  const unsigned short* srcA[2];
  const unsigned short* srcB[2];
  int dstoff[2];
#pragma unroll
  for (int q = 0; q < 2; q++) {
    int brow = wave * 32 + q * 16 + lr4;
    int p = m0 + brow; if (p > NTOK - 1) p = NTOK - 1;
    int arow = perm[p];
    srcA[q] = Xc + (size_t)arow * DIM + kc * 8;
    srcB[q] = B + (size_t)(c0 + brow) * DIM + kc * 8;
    dstoff[q] = (wave * 32 + q * 16) * 32;
  }

  floatx4 acc[4][4];
  floatx4 zero = {0.f, 0.f, 0.f, 0.f};
#pragma unroll
  for (int i = 0; i < 4; i++)
#pragma unroll
    for (int j = 0; j < 4; j++) acc[i][j] = zero;

  int rowA[4], rowB[4];
#pragma unroll
  for (int i = 0; i < 4; i++) {
    rowA[i] = (wr * 64 + i * 16 + m16) * 32;
    rowB[i] = (wc * 64 + i * 16 + m16) * 32;
  }
  int roff = (grp ^ (m16 & 3)) * 8;  // read-side inverse of the staging swizzle

  // prologue: K-tile 0 into buffer 0
#pragma unroll
  for (int q = 0; q < 2; q++) async_cp16(srcA[q], lds + dstoff[q]);
#pragma unroll
  for (int q = 0; q < 2; q++) async_cp16(srcB[q], lds + 4096 + dstoff[q]);
#pragma unroll
  for (int q = 0; q < 2; q++) { srcA[q] += 32; srcB[q] += 32; }

  const int kIters = DIM / 32;  // 32
  int p = 0;
  for (int it = 0; it < kIters; ++it) {
    __syncthreads();  // drains vmcnt: current buffer's loads (issued last iter) landed
    unsigned short* Acur = lds + p * 8192;
    unsigned short* Bcur = Acur + 4096;
    if (it + 1 < kIters) {
      unsigned short* An = lds + (p ^ 1) * 8192;
#pragma unroll
      for (int q = 0; q < 2; q++) async_cp16(srcA[q], An + dstoff[q]);
#pragma unroll
      for (int q = 0; q < 2; q++) async_cp16(srcB[q], An + 4096 + dstoff[q]);
#pragma unroll
      for (int q = 0; q < 2; q++) { srcA[q] += 32; srcB[q] += 32; }
    }
    bf16x8 af[4], bfr[4];
#pragma unroll
    for (int i = 0; i < 4; i++) af[i] = *(const bf16x8*)&Acur[rowA[i] + roff];
#pragma unroll
    for (int j = 0; j < 4; j++) bfr[j] = *(const bf16x8*)&Bcur[rowB[j] + roff];
#pragma unroll
    for (int i = 0; i < 4; i++)
#pragma unroll
      for (int j = 0; j < 4; j++)
        acc[i][j] = __builtin_amdgcn_mfma_f32_16x16x32_bf16(af[i], bfr[j], acc[i][j], 0, 0, 0);
    p ^= 1;
  }
  __syncthreads();  // protect LDS reuse by the epilogue

  float bs[4];
#pragma unroll
  for (int j = 0; j < 4; j++) bs[j] = bias[(size_t)e * FDIM + c0 + wc * 64 + j * 16 + m16];

  // Epilogue staging: stride 64, col XOR-swizzled by (((row>>1)&7)<<3). Conflict-free
  // both sides (r4: verified, 0 conflicts).
  unsigned short* st = lds + wave * 4096;
#pragma unroll
  for (int i = 0; i < 4; i++)
#pragma unroll
    for (int j = 0; j < 4; j++)
#pragma unroll
      for (int r = 0; r < 4; r++) {
        int row = i * 16 + grp * 4 + r;
        int scol = (j * 16 + m16) ^ (((row >> 1) & 7) << 3);
        st[row * 64 + scol] = f2b(gelu_f(acc[i][j][r] + bs[j]));
      }
  __syncthreads();
  int lr8 = lane >> 3, c8 = (lane & 7) * 8;
  int colb = c0 + wc * 64 + c8;
#pragma unroll
  for (int rr = 0; rr < 8; rr++) {
    int row = rr * 8 + lr8;
    int gm = wr * 64 + row;
    if (gm < cnt) {
      int scol = c8 ^ (((row >> 1) & 7) << 3);
      *(uint4*)&Hout[(size_t)(m0 + gm) * FDIM + colb] = *(const uint4*)&st[row * 64 + scol];
    }
  }
}

// ---------------- GEMM2 full-K, double-buffered LDS (r3: -40us vs single-buffer) ----------------
__global__ __launch_bounds__(256) void gemm2_k(
    const unsigned short* __restrict__ Hmat, const unsigned short* __restrict__ W2b,
    const float* __restrict__ b2, float* __restrict__ out,
    const int* __restrict__ perm, const float* __restrict__ gate_p,
    const int* __restrict__ ctrl) {
  __shared__ unsigned short lds[32768];  // 2 x (A 8192 + B 8192)

  int mt = blockIdx.y;
  int e, m0, cnt, ntiles;
  expert_tile(ctrl, mt, e, m0, cnt, ntiles);
  if (mt >= ntiles) return;
  int c0 = blockIdx.x * 128;
  const unsigned short* B = W2b + (size_t)e * DIM * FDIM;

  int tid = threadIdx.x;
  int lane = tid & 63, wave = tid >> 6;
  int wr = wave >> 1, wc = wave & 1;
  int grp = lane >> 4, m16 = lane & 15;

  int lr = lane >> 3;
  int cchunk = (lane & 7) ^ lr;
  const unsigned short* srcA[4];
  const unsigned short* srcB[4];
  int dstoff[4];
#pragma unroll
  for (int q = 0; q < 4; q++) {
    int brow = wave * 32 + q * 8;
    int arow = m0 + brow + lr; if (arow > NTOK - 1) arow = NTOK - 1;
    srcA[q] = Hmat + (size_t)arow * FDIM + cchunk * 8;
    srcB[q] = B + (size_t)(c0 + brow + lr) * FDIM + cchunk * 8;
    dstoff[q] = brow * 64;
  }

  floatx4 acc[4][4];
  floatx4 zero = {0.f, 0.f, 0.f, 0.f};
#pragma unroll
  for (int i = 0; i < 4; i++)
#pragma unroll
    for (int j = 0; j < 4; j++) acc[i][j] = zero;

  int x7 = m16 & 7;
  int rowA[4], rowB[4];
#pragma unroll
  for (int i = 0; i < 4; i++) {
    rowA[i] = (wr * 64 + i * 16 + m16) * 64;
    rowB[i] = (wc * 64 + i * 16 + m16) * 64;
  }

  // prologue: stage K-tile 0 into buffer 0
#pragma unroll
  for (int q = 0; q < 4; q++) async_cp16(srcA[q], lds + dstoff[q]);
#pragma unroll
  for (int q = 0; q < 4; q++) async_cp16(srcB[q], lds + 8192 + dstoff[q]);
#pragma unroll
  for (int q = 0; q < 4; q++) { srcA[q] += 64; srcB[q] += 64; }

  const int kIters = FDIM / 64;  // 64
  int p = 0;
  for (int it = 0; it < kIters; ++it) {
    __syncthreads();
    unsigned short* Acur = lds + p * 16384;
    unsigned short* Bcur = Acur + 8192;
    if (it + 1 < kIters) {
      unsigned short* An = lds + (p ^ 1) * 16384;
      unsigned short* Bn = An + 8192;
#pragma unroll
      for (int q = 0; q < 4; q++) async_cp16(srcA[q], An + dstoff[q]);
#pragma unroll
      for (int q = 0; q < 4; q++) async_cp16(srcB[q], Bn + dstoff[q]);
#pragma unroll
      for (int q = 0; q < 4; q++) { srcA[q] += 64; srcB[q] += 64; }
    }
    bf16x8 af[2][4], bfr[2][4];
#pragma unroll
    for (int h = 0; h < 2; h++) {
      int off = (((h << 2) | grp) ^ x7) << 3;
#pragma unroll
      for (int i = 0; i < 4; i++) {
        af[h][i]  = *(const bf16x8*)&Acur[rowA[i] + off];
        bfr[h][i] = *(const bf16x8*)&Bcur[rowB[i] + off];
      }
    }
#pragma unroll
    for (int h = 0; h < 2; h++)
#pragma unroll
      for (int i = 0; i < 4; i++)
#pragma unroll
        for (int j = 0; j < 4; j++)
          acc[i][j] = __builtin_amdgcn_mfma_f32_16x16x32_bf16(af[h][i], bfr[h][j], acc[i][j], 0, 0, 0);
    p ^= 1;
  }

  float bs[4];
#pragma unroll
  for (int j = 0; j < 4; j++) bs[j] = b2[(size_t)e * DIM + c0 + wc * 64 + j * 16 + m16];

#pragma unroll
  for (int i = 0; i < 4; i++) {
    int rb = wr * 64 + i * 16 + grp * 4;
#pragma unroll
    for (int r = 0; r < 4; r++) {
      int lm = rb + r;
      if (lm < cnt) {
        int t = perm[m0 + lm];
        float g = gate_p[m0 + lm];
#pragma unroll
        for (int j = 0; j < 4; j++) {
          int col = c0 + wc * 64 + j * 16 + m16;
          out[(size_t)t * DIM + col] = (acc[i][j][r] + bs[j]) * g;
        }
      }
    }
  }
}

extern "C" void kernel_launch(void* const* d_in, const int* in_sizes, int n_in,
                              void* d_out, int out_size, void* d_ws, size_t ws_size,
                              hipStream_t stream) {
  const float* x  = (const float*)d_in[0];
  const float* W1 = (const float*)d_in[1];
  const float* b1 = (const float*)d_in[2];
  const float* W2 = (const float*)d_in[3];
  const float* b2 = (const float*)d_in[4];
  const float* Wr = (const float*)d_in[5];
  const float* br = (const float*)d_in[6];
  float* out = (float*)d_out;

  char* w = (char*)d_ws;
  int*   ctrl   = (int*)w;
  int*   idx    = (int*)(w + 1024);
  float* gate   = (float*)(w + 1024 + 4 * NTOK);
  int*   perm   = (int*)(w + 1024 + 8 * NTOK);
  float* gate_p = (float*)(w + 1024 + 12 * NTOK);
  unsigned short* Xc  = (unsigned short*)(w + (1ull << 18));    // 16.8 MB, token order
  unsigned short* H   = (unsigned short*)(w + (20ull << 20));   // 67.1 MB
  unsigned short* W1b = (unsigned short*)(w + (88ull << 20));   // 67.1 MB
  unsigned short* W2b = (unsigned short*)(w + (156ull << 20));  // 67.1 MB

  hipMemsetAsync(ctrl, 0, 256, stream);
  // transpose first: its sweep runs before Xc is produced, so Xc stays L3-warm for gemm1
  transpose_cvt2_k<<<dim3(64, 16, 16), 256, 0, stream>>>(W1, W1b, W2, W2b);
  router_cvt_k<<<NTOK / 4, 256, 0, stream>>>(x, Wr, br, idx, gate, ctrl, Xc);
  perm_k<<<NTOK / 256, 256, 0, stream>>>(idx, gate, ctrl, perm, gate_p);
  gemm1_k<<<dim3(FDIM / 128, 72), 256, 0, stream>>>(Xc, W1b, b1, H, ctrl, perm);
  gemm2_k<<<dim3(DIM / 128, 72), 256, 0, stream>>>(H, W2b, b2, out, perm, gate_p, ctrl);
}